// Round 6
// baseline (720.829 us; speedup 1.0000x reference)
//
#include <hip/hip_runtime.h>
#include <stdint.h>

typedef __bf16 bf16_t;
typedef __bf16 bf16x8 __attribute__((ext_vector_type(8)));
typedef __bf16 bf16x4 __attribute__((ext_vector_type(4)));
typedef float f32x4 __attribute__((ext_vector_type(4)));

// Async global->LDS, 16B per lane (wave-uniform base + lane*16).
#define GLOAD16(gp, lp)                                                        \
    __builtin_amdgcn_global_load_lds(                                          \
        (const __attribute__((address_space(1))) void*)(gp),                   \
        (__attribute__((address_space(3))) void*)(lp), 16, 0, 0)

// BK=32 tiles, row = 32 bf16 = 64 B. XOR swizzle (R2-verified, conflicts->0):
// chunk q of row r lives in slot q ^ ((r>>1)&3); loader thread t (row=t>>2)
// fetches global chunk (t&3) ^ ((t>>3)&3), LDS dest linear t*16B.
//
// Ping-pong pipeline (1 barrier/iter): at iter k the barrier (a) completes
// GLOAD(k) issued one full compute-phase earlier (vmcnt drain ~free) and
// (b) retires all reads of the other buffer; then GLOAD(k+1) is issued into
// the idle buffer BEFORE the ds_read+MFMA phase. Four separate __shared__
// arrays + 2x unroll give static disambiguation (no spurious vmcnt waits).

// ---------------------------------------------------------------------------
// All fp32 -> bf16 conversions in ONE launch (7 segments).
// ---------------------------------------------------------------------------
__global__ __launch_bounds__(256) void cvt_all_kernel(
    const float* __restrict__ x, const float* __restrict__ Wgu,
    const float* __restrict__ Bgu, const float* __restrict__ Wd,
    const float* __restrict__ Bd, const float* __restrict__ Agu,
    const float* __restrict__ Ad, bf16_t* __restrict__ X1,
    bf16_t* __restrict__ W1, bf16_t* __restrict__ W2,
    bf16_t* __restrict__ Abf, bf16_t* __restrict__ Adbf) {
    int b = blockIdx.x;
    const float* src;
    bf16_t* dst;
    int cshift, cmask, ldd, coff, lb;
    if (b < 16384) {
        src = x; dst = X1; cshift = 11; cmask = 2047; ldd = 2112; coff = 0; lb = b;
    } else if (b < 32768) {
        src = Wgu; dst = W1; cshift = 11; cmask = 2047; ldd = 2112; coff = 0; lb = b - 16384;
    } else if (b < 33280) {
        src = Bgu; dst = W1; cshift = 6; cmask = 63; ldd = 2112; coff = 2048; lb = b - 32768;
    } else if (b < 41472) {
        src = Wd; dst = W2; cshift = 12; cmask = 4095; ldd = 4160; coff = 0; lb = b - 33280;
    } else if (b < 41600) {
        src = Bd; dst = W2; cshift = 6; cmask = 63; ldd = 4160; coff = 4096; lb = b - 41472;
    } else if (b < 41728) {
        src = Agu; dst = Abf; cshift = 11; cmask = 2047; ldd = 2048; coff = 0; lb = b - 41600;
    } else {
        src = Ad; dst = Adbf; cshift = 12; cmask = 4095; ldd = 4096; coff = 0; lb = b - 41728;
    }
    int idx = (lb * 256 + threadIdx.x) << 2;
    int r = idx >> cshift;
    int c = idx & cmask;
    float4 v = *(const float4*)(src + idx);
    bf16x4 o = {(bf16_t)v.x, (bf16_t)v.y, (bf16_t)v.z, (bf16_t)v.w};
    *(bf16x4*)(dst + (size_t)r * ldd + coff + c) = o;
}

// ---------------------------------------------------------------------------
// LoRA GEMM, ping-pong BK=32: t = 0.25 * (A[M x K] @ Bw[64 x K]^T) -> bf16
// into dst cols [coff,coff+64). BM=64/block, grid = M/64.
// ---------------------------------------------------------------------------
__global__ __launch_bounds__(256) void lora_kernel(const bf16_t* __restrict__ A,
                                                   int lda,
                                                   const bf16_t* __restrict__ Bw,
                                                   int K, bf16_t* __restrict__ dst,
                                                   int ldd, int coff) {
    __shared__ __align__(16) bf16_t As0[64 * 32];
    __shared__ __align__(16) bf16_t Bs0[64 * 32];
    __shared__ __align__(16) bf16_t As1[64 * 32];
    __shared__ __align__(16) bf16_t Bs1[64 * 32];
    const int t = threadIdx.x;
    const int m0 = blockIdx.x * 64;
    const int lane = t & 63, w = t >> 6;
    const int ln15 = lane & 15, q = lane >> 4;

    const int lrow = t >> 2;
    const int lchunk = (t & 3) ^ ((t >> 3) & 3);
    const bf16_t* ga = A + (size_t)(m0 + lrow) * lda + lchunk * 8;
    const bf16_t* gb = Bw + (size_t)lrow * K + lchunk * 8;
    const int ld = t * 8;

    const f32x4 z = {0.f, 0.f, 0.f, 0.f};
    f32x4 acc[4];
#pragma unroll
    for (int j = 0; j < 4; ++j) acc[j] = z;

    const int arow = w * 16 + ln15;
    const int aoff = arow * 32 + ((q ^ ((arow >> 1) & 3)) << 3);
    int boff[4];
#pragma unroll
    for (int j = 0; j < 4; ++j) {
        int r = j * 16 + ln15;
        boff[j] = r * 32 + ((q ^ ((r >> 1) & 3)) << 3);
    }

#define LORA_COMPUTE(AS, BS)                                                   \
    {                                                                          \
        bf16x8 av = *(const bf16x8*)(AS + aoff);                               \
        _Pragma("unroll") for (int j = 0; j < 4; ++j) {                        \
            bf16x8 bv = *(const bf16x8*)(BS + boff[j]);                        \
            acc[j] = __builtin_amdgcn_mfma_f32_16x16x32_bf16(av, bv, acc[j], 0, 0, 0); \
        }                                                                      \
    }

    GLOAD16(ga, As0 + ld);
    GLOAD16(gb, Bs0 + ld);
    for (int kt = 0; kt < K; kt += 64) {
        __syncthreads();
        GLOAD16(ga + kt + 32, As1 + ld);
        GLOAD16(gb + kt + 32, Bs1 + ld);
        LORA_COMPUTE(As0, Bs0)
        __syncthreads();
        if (kt + 64 < K) {
            GLOAD16(ga + kt + 64, As0 + ld);
            GLOAD16(gb + kt + 64, Bs0 + ld);
        }
        LORA_COMPUTE(As1, Bs1)
    }

#pragma unroll
    for (int j = 0; j < 4; ++j)
#pragma unroll
        for (int rg = 0; rg < 4; ++rg) {
            int m = m0 + w * 16 + q * 4 + rg;
            dst[(size_t)m * ldd + coff + j * 16 + ln15] = (bf16_t)(acc[j][rg] * 0.25f);
        }
}

// ---------------------------------------------------------------------------
// GEMM1 fused, ping-pong BK=32: gate_up = X1[8192 x 2112] @ Wc^T + SwiGLU.
// Block: 128 rows x (64 gate + 64 up cols). 66 iters, 16 MFMA/wave/iter,
// 1 cheap barrier/iter. LDS 32 KB, 4 blocks/CU.
// ---------------------------------------------------------------------------
__global__ __launch_bounds__(256, 4) void gemm1_kernel(const bf16_t* __restrict__ X,
                                                       const bf16_t* __restrict__ Wc,
                                                       bf16_t* __restrict__ X2) {
    constexpr int LDA = 2112, LDW = 2112, LDX2 = 4160, K = 2112;
    __shared__ __align__(16) bf16_t As0[128 * 32];
    __shared__ __align__(16) bf16_t Bs0[128 * 32];
    __shared__ __align__(16) bf16_t As1[128 * 32];
    __shared__ __align__(16) bf16_t Bs1[128 * 32];
    const int t = threadIdx.x;
    const int n0 = blockIdx.x * 64;
    const int m0 = blockIdx.y * 128;
    const int lane = t & 63, w = t >> 6, wr = w >> 1, wc = w & 1;
    const int ln15 = lane & 15, q = lane >> 4;

    const int lrow = t >> 2;
    const int lchunk = (t & 3) ^ ((t >> 3) & 3);
    const bf16_t* ga = X + (size_t)(m0 + lrow) * LDA + lchunk * 8;
    const bf16_t* ga2 = ga + (size_t)64 * LDA;
    const bf16_t* gbg = Wc + (size_t)(n0 + lrow) * LDW + lchunk * 8;          // gate
    const bf16_t* gbu = Wc + (size_t)(4096 + n0 + lrow) * LDW + lchunk * 8;   // up
    const int ld = t * 8;

    const f32x4 z = {0.f, 0.f, 0.f, 0.f};
    f32x4 accg[4][2], accu[4][2];
#pragma unroll
    for (int i = 0; i < 4; ++i)
#pragma unroll
        for (int j = 0; j < 2; ++j) {
            accg[i][j] = z;
            accu[i][j] = z;
        }

    int aoff[4], bgoff[2];
#pragma unroll
    for (int i = 0; i < 4; ++i) {
        int row = wr * 64 + i * 16 + ln15;
        aoff[i] = row * 32 + ((q ^ ((row >> 1) & 3)) << 3);
    }
#pragma unroll
    for (int j = 0; j < 2; ++j) {
        int row = wc * 32 + j * 16 + ln15;
        bgoff[j] = row * 32 + ((q ^ ((row >> 1) & 3)) << 3);  // up = +2048, same swz
    }

#define G1_COMPUTE(AS, BS)                                                     \
    {                                                                          \
        bf16x8 av[4], bg[2], bu[2];                                            \
        _Pragma("unroll") for (int i = 0; i < 4; ++i)                          \
            av[i] = *(const bf16x8*)(AS + aoff[i]);                            \
        _Pragma("unroll") for (int j = 0; j < 2; ++j) {                        \
            bg[j] = *(const bf16x8*)(BS + bgoff[j]);                           \
            bu[j] = *(const bf16x8*)(BS + bgoff[j] + 2048);                    \
        }                                                                      \
        _Pragma("unroll") for (int i = 0; i < 4; ++i)                          \
            _Pragma("unroll") for (int j = 0; j < 2; ++j) {                    \
                accg[i][j] = __builtin_amdgcn_mfma_f32_16x16x32_bf16(av[i], bg[j], accg[i][j], 0, 0, 0); \
                accu[i][j] = __builtin_amdgcn_mfma_f32_16x16x32_bf16(av[i], bu[j], accu[i][j], 0, 0, 0); \
            }                                                                  \
    }

    GLOAD16(ga, As0 + ld);
    GLOAD16(ga2, As0 + 2048 + ld);
    GLOAD16(gbg, Bs0 + ld);
    GLOAD16(gbu, Bs0 + 2048 + ld);
    for (int kt = 0; kt < K; kt += 64) {
        __syncthreads();
        GLOAD16(ga + kt + 32, As1 + ld);
        GLOAD16(ga2 + kt + 32, As1 + 2048 + ld);
        GLOAD16(gbg + kt + 32, Bs1 + ld);
        GLOAD16(gbu + kt + 32, Bs1 + 2048 + ld);
        G1_COMPUTE(As0, Bs0)
        __syncthreads();
        if (kt + 64 < K) {
            GLOAD16(ga + kt + 64, As0 + ld);
            GLOAD16(ga2 + kt + 64, As0 + 2048 + ld);
            GLOAD16(gbg + kt + 64, Bs0 + ld);
            GLOAD16(gbu + kt + 64, Bs0 + 2048 + ld);
        }
        G1_COMPUTE(As1, Bs1)
    }

#pragma unroll
    for (int i = 0; i < 4; ++i)
#pragma unroll
        for (int j = 0; j < 2; ++j)
#pragma unroll
            for (int rg = 0; rg < 4; ++rg) {
                int m = m0 + wr * 64 + i * 16 + q * 4 + rg;
                int d = n0 + wc * 32 + j * 16 + ln15;
                float g = accg[i][j][rg];
                float u = accu[i][j][rg];
                float h = u * g / (1.f + __expf(-g));  // up * silu(gate)
                X2[(size_t)m * LDX2 + d] = (bf16_t)h;
            }
}

// ---------------------------------------------------------------------------
// GEMM2, ping-pong BK=32: out = X2[8192 x 4160] @ Wdc[2048 x 4160]^T, fp32.
// 130 iters, 16 MFMA/wave/iter, 1 barrier/iter. grid 1024 = 1 round @ 4/CU.
// ---------------------------------------------------------------------------
__global__ __launch_bounds__(256, 4) void gemm2_kernel(const bf16_t* __restrict__ X2,
                                                       const bf16_t* __restrict__ Wdc,
                                                       float* __restrict__ out) {
    constexpr int LDA = 4160, LDB = 4160, K = 4160, LDO = 2048;
    __shared__ __align__(16) bf16_t As0[128 * 32];
    __shared__ __align__(16) bf16_t Bs0[128 * 32];
    __shared__ __align__(16) bf16_t As1[128 * 32];
    __shared__ __align__(16) bf16_t Bs1[128 * 32];
    const int t = threadIdx.x;
    const int n0 = blockIdx.x * 128;
    const int m0 = blockIdx.y * 128;
    const int lane = t & 63, w = t >> 6, wr = w >> 1, wc = w & 1;
    const int ln15 = lane & 15, q = lane >> 4;

    const int lrow = t >> 2;
    const int lchunk = (t & 3) ^ ((t >> 3) & 3);
    const bf16_t* ga = X2 + (size_t)(m0 + lrow) * LDA + lchunk * 8;
    const bf16_t* ga2 = ga + (size_t)64 * LDA;
    const bf16_t* gb = Wdc + (size_t)(n0 + lrow) * LDB + lchunk * 8;
    const bf16_t* gb2 = gb + (size_t)64 * LDB;
    const int ld = t * 8;

    const f32x4 z = {0.f, 0.f, 0.f, 0.f};
    f32x4 acc[4][4];
#pragma unroll
    for (int i = 0; i < 4; ++i)
#pragma unroll
        for (int j = 0; j < 4; ++j) acc[i][j] = z;

    int aoff[4], boff[4];
#pragma unroll
    for (int i = 0; i < 4; ++i) {
        int rowa = wr * 64 + i * 16 + ln15;
        int rowb = wc * 64 + i * 16 + ln15;
        aoff[i] = rowa * 32 + ((q ^ ((rowa >> 1) & 3)) << 3);
        boff[i] = rowb * 32 + ((q ^ ((rowb >> 1) & 3)) << 3);
    }

#define G2_COMPUTE(AS, BS)                                                     \
    {                                                                          \
        bf16x8 av[4], bv[4];                                                   \
        _Pragma("unroll") for (int i = 0; i < 4; ++i) {                        \
            av[i] = *(const bf16x8*)(AS + aoff[i]);                            \
            bv[i] = *(const bf16x8*)(BS + boff[i]);                            \
        }                                                                      \
        _Pragma("unroll") for (int i = 0; i < 4; ++i)                          \
            _Pragma("unroll") for (int j = 0; j < 4; ++j)                      \
                acc[i][j] = __builtin_amdgcn_mfma_f32_16x16x32_bf16(av[i], bv[j], acc[i][j], 0, 0, 0); \
    }

    GLOAD16(ga, As0 + ld);
    GLOAD16(ga2, As0 + 2048 + ld);
    GLOAD16(gb, Bs0 + ld);
    GLOAD16(gb2, Bs0 + 2048 + ld);
    for (int kt = 0; kt < K; kt += 64) {
        __syncthreads();
        GLOAD16(ga + kt + 32, As1 + ld);
        GLOAD16(ga2 + kt + 32, As1 + 2048 + ld);
        GLOAD16(gb + kt + 32, Bs1 + ld);
        GLOAD16(gb2 + kt + 32, Bs1 + 2048 + ld);
        G2_COMPUTE(As0, Bs0)
        __syncthreads();
        if (kt + 64 < K) {
            GLOAD16(ga + kt + 64, As0 + ld);
            GLOAD16(ga2 + kt + 64, As0 + 2048 + ld);
            GLOAD16(gb + kt + 64, Bs0 + ld);
            GLOAD16(gb2 + kt + 64, Bs0 + 2048 + ld);
        }
        G2_COMPUTE(As1, Bs1)
    }

#pragma unroll
    for (int i = 0; i < 4; ++i)
#pragma unroll
        for (int j = 0; j < 4; ++j)
#pragma unroll
            for (int rg = 0; rg < 4; ++rg) {
                int m = m0 + wr * 64 + i * 16 + q * 4 + rg;
                int n = n0 + wc * 64 + j * 16 + ln15;
                out[(size_t)m * LDO + n] = acc[i][j][rg];
            }
}

// ---------------------------------------------------------------------------
// Workspace layout (bytes):
//   X1   @ 0         : 8192 x 2112 bf16   [x | 0.25*x@A_gu^T]
//   W1   @ 34603008  : 8192 x 2112 bf16   [W_gu | B_gu]
//   X2   @ 69206016  : 8192 x 4160 bf16   [h | 0.25*h@A_d^T]
//   W2   @ 137363456 : 2048 x 4160 bf16   [W_d | B_d]
//   Abf  @ 154402816 : 64 x 2048 bf16
//   Adbf @ 154664960 : 64 x 4096 bf16
// ---------------------------------------------------------------------------
extern "C" void kernel_launch(void* const* d_in, const int* in_sizes, int n_in,
                              void* d_out, int out_size, void* d_ws, size_t ws_size,
                              hipStream_t stream) {
    const float* x = (const float*)d_in[0];
    const float* Wgu = (const float*)d_in[1];
    const float* Agu = (const float*)d_in[2];
    const float* Bgu = (const float*)d_in[3];
    const float* Wd = (const float*)d_in[4];
    const float* Ad = (const float*)d_in[5];
    const float* Bd = (const float*)d_in[6];
    float* out = (float*)d_out;

    char* ws = (char*)d_ws;
    bf16_t* X1 = (bf16_t*)(ws);
    bf16_t* W1 = (bf16_t*)(ws + 34603008);
    bf16_t* X2 = (bf16_t*)(ws + 69206016);
    bf16_t* W2 = (bf16_t*)(ws + 137363456);
    bf16_t* Abf = (bf16_t*)(ws + 154402816);
    bf16_t* Adbf = (bf16_t*)(ws + 154664960);

    // all fp32 -> bf16 conversions, single launch
    cvt_all_kernel<<<41984, 256, 0, stream>>>(x, Wgu, Bgu, Wd, Bd, Agu, Ad,
                                              X1, W1, W2, Abf, Adbf);

    // t1 = 0.25 * x @ A_gu^T  -> X1 cols [2048,2112)
    lora_kernel<<<128, 256, 0, stream>>>(X1, 2112, Abf, 2048, X1, 2112, 2048);
    // fused gate_up GEMM + SwiGLU -> X2 cols [0,4096)
    gemm1_kernel<<<dim3(64, 64), 256, 0, stream>>>(X1, W1, X2);
    // t2 = 0.25 * h @ A_d^T -> X2 cols [4096,4160)
    lora_kernel<<<128, 256, 0, stream>>>(X2, 4160, Adbf, 4096, X2, 4160, 4096);
    // out = X2 @ [W_d|B_d]^T
    gemm2_kernel<<<dim3(16, 64), 256, 0, stream>>>(X2, W2, out);
}